// Round 3
// baseline (930.874 us; speedup 1.0000x reference)
//
#include <hip/hip_runtime.h>
#include <hip/hip_fp16.h>

// Problem constants (fixed by reference setup_inputs):
//   K3=27, PAIRS_PER_K=131072 (=2^17), N_VOX=262144 (=2^18), C_IN=C_OUT=32
//   M = 3,538,944 pairs. out = [262144][32] fp32.
//
// Round-2 lessons (rocprof): per-thread LDS weight reads cost 3x the FMA
// floor (7M ds_read_b128 wave-instrs); returning atomics run ~12G/s.
// Round-3: dense (k,v) ownership table -> wave-uniform k loop in gather
// (W via s_load, zero LDS), overflow (multi-hit cells, ~21% of pairs)
// via per-voxel slot list.

#define N_VOX    262144
#define LOG2_NV  18
#define C_CH     32
#define K3       27
#define LOG2_PPK 17
#define BLOCK    256
#define FLAG_FIN 0x40000000

// ===========================================================================
// PRIMARY SCHEME
// ===========================================================================

// Pass A: last-writer-wins claim. Plain 4B scattered stores, no atomics.
__global__ __launch_bounds__(BLOCK) void passA_kernel(
    const int2* __restrict__ nbmap, int* __restrict__ T, int M) {
  int p = blockIdx.x * BLOCK + threadIdx.x;
  if (p >= M) return;
  int2 nb = nbmap[p];
  int k = p >> LOG2_PPK;
  T[(k << LOG2_NV) + nb.y] = p;
}

// Pass B: owner finalizes cell with in_idx; losers append to overflow list
// (returning atomic only for the ~21% multi-hit pairs).
__global__ __launch_bounds__(BLOCK) void passB_kernel(
    const int2* __restrict__ nbmap, int* __restrict__ T,
    int* __restrict__ ovf_cnt, int* __restrict__ ovf, int S2, int M) {
  int p = blockIdx.x * BLOCK + threadIdx.x;
  if (p >= M) return;
  int2 nb = nbmap[p];
  int k = p >> LOG2_PPK;
  int idx = (k << LOG2_NV) + nb.y;
  if (T[idx] == p) {
    T[idx] = FLAG_FIN | nb.x;           // in_idx < 2^18, bit30 = finalized
  } else {
    int pos = atomicAdd(&ovf_cnt[nb.y], 1);
    if (pos < S2) ovf[(pos << LOG2_NV) + nb.y] = (k << LOG2_NV) | nb.x;
  }
}

// Gather: lane = voxel. Dense k loop with WAVE-UNIFORM weight base
// -> compiler emits s_load for W, v_fmac_f32 acc, sW, vA. Zero LDS.
__global__ __launch_bounds__(BLOCK) void gather_dense_kernel(
    const float* __restrict__ in_feature,
    const float* __restrict__ kernel_w,   // [27][32][32] f32
    const float* __restrict__ bias,
    const int* __restrict__ T,
    const int* __restrict__ ovf_cnt,
    const int* __restrict__ ovf,
    float* __restrict__ out, int S2) {
  int v = blockIdx.x * BLOCK + threadIdx.x;

  float acc[C_CH];
#pragma unroll
  for (int c = 0; c < C_CH; ++c) acc[c] = bias[c];   // uniform -> s_load

  int t = T[v];                                      // probe k=0
#pragma unroll 1
  for (int k = 0; k < K3; ++k) {
    // issue next probe before the FMA block so its latency hides
    int t_next = (k + 1 < K3) ? T[((k + 1) << LOG2_NV) + v] : -1;
    if (t >= 0) {                                    // cells: -1 or FLAG|in
      int in = t & 0x3FFFF;
      const float4* ar = (const float4*)(in_feature + ((long)in << 5));
      float a[C_CH];
#pragma unroll
      for (int q = 0; q < 8; ++q) ((float4*)a)[q] = ar[q];
      const float* __restrict__ Wk = kernel_w + (k << 10);  // wave-uniform
#pragma unroll
      for (int i = 0; i < C_CH; ++i) {
        float av = a[i];
#pragma unroll
        for (int c = 0; c < C_CH; ++c)
          acc[c] = fmaf(av, Wk[(i << 5) + c], acc[c]);
      }
    }
    t = t_next;
  }

  // Overflow contributions (mean 2.9/voxel): divergent k, W from L1/L2.
  int n2 = ovf_cnt[v];
  if (n2 > S2) n2 = S2;
  for (int j = 0; j < n2; ++j) {
    int s = ovf[(j << LOG2_NV) + v];
    int k2 = s >> LOG2_NV;
    int in = s & 0x3FFFF;
    const float4* ar = (const float4*)(in_feature + ((long)in << 5));
    float a[C_CH];
#pragma unroll
    for (int q = 0; q < 8; ++q) ((float4*)a)[q] = ar[q];
    const float* __restrict__ Wk = kernel_w + (k2 << 10);
#pragma unroll
    for (int i = 0; i < C_CH; ++i) {
      float av = a[i];
#pragma unroll
      for (int c = 0; c < C_CH; ++c)
        acc[c] = fmaf(av, Wk[(i << 5) + c], acc[c]);
    }
  }

  float4* orow = (float4*)(out + ((long)v << 5));
#pragma unroll
  for (int q = 0; q < 8; ++q) orow[q] = ((float4*)acc)[q];
}

// ===========================================================================
// FALLBACK 1: round-2 slot scheme (used if ws too small for dense table)
// ===========================================================================
#define GBLK 512
#define WSTRIDE 1032

__global__ __launch_bounds__(BLOCK) void build_kernel(
    const int2* __restrict__ nbmap, int* __restrict__ cnt,
    int* __restrict__ slots, int S, int M) {
  int p = blockIdx.x * BLOCK + threadIdx.x;
  if (p >= M) return;
  int2 nb = nbmap[p];
  int k = p >> LOG2_PPK;
  int pos = atomicAdd(&cnt[nb.y], 1);
  if (pos < S) slots[pos * N_VOX + nb.y] = (k << LOG2_NV) | nb.x;
}

__global__ __launch_bounds__(GBLK) void gather_kernel(
    const float* __restrict__ in_feature,
    const float* __restrict__ kernel_w,
    const float* __restrict__ bias,
    const int* __restrict__ cnt,
    const int* __restrict__ slots,
    float* __restrict__ out, int S) {
  __shared__ __half Wlds[K3 * WSTRIDE];
  for (int idx = threadIdx.x; idx < K3 * 1024; idx += GBLK) {
    int k = idx >> 10, r = idx & 1023;
    Wlds[k * WSTRIDE + r] = __float2half(kernel_w[idx]);
  }
  __syncthreads();
  int v = blockIdx.x * GBLK + threadIdx.x;
  if (v >= N_VOX) return;
  int n = cnt[v];
  if (n > S) n = S;
  float acc[C_CH];
  const float4* b4 = (const float4*)bias;
#pragma unroll
  for (int q = 0; q < 8; ++q) ((float4*)acc)[q] = b4[q];
  for (int j = 0; j < n; ++j) {
    int s = slots[j * N_VOX + v];
    int k = s >> LOG2_NV;
    int in = s & 0x3FFFF;
    float a[C_CH];
    const float4* arow = (const float4*)(in_feature + (long)in * C_CH);
#pragma unroll
    for (int q = 0; q < 8; ++q) ((float4*)a)[q] = arow[q];
    const __half* Wk = &Wlds[k * WSTRIDE];
#pragma unroll
    for (int i = 0; i < C_CH; ++i) {
      const float av = a[i];
      const float4* wrow = (const float4*)(Wk + i * C_CH);
#pragma unroll
      for (int q = 0; q < 4; ++q) {
        float4 wv = wrow[q];
        const __half2* h2 = (const __half2*)&wv;
#pragma unroll
        for (int t = 0; t < 4; ++t) {
          float2 f = __half22float2(h2[t]);
          int c = q * 8 + t * 2;
          acc[c] = fmaf(av, f.x, acc[c]);
          acc[c + 1] = fmaf(av, f.y, acc[c + 1]);
        }
      }
    }
  }
  float4* orow = (float4*)(out + (long)v * C_CH);
#pragma unroll
  for (int q = 0; q < 8; ++q) orow[q] = ((float4*)acc)[q];
}

// ===========================================================================
// FALLBACK 2: direct-atomic (round-1), if ws is tiny
// ===========================================================================
__global__ __launch_bounds__(BLOCK) void init_bias_kernel(
    float* __restrict__ out, const float* __restrict__ bias, int n4) {
  int idx = blockIdx.x * blockDim.x + threadIdx.x;
  if (idx >= n4) return;
  ((float4*)out)[idx] = ((const float4*)bias)[idx & 7];
}

__global__ __launch_bounds__(BLOCK) void scatter_conv_kernel(
    const float* __restrict__ in_feature,
    const float* __restrict__ kernel_w,
    const int* __restrict__ nbmap,
    float* __restrict__ out) {
  const int k = blockIdx.x >> 9;
  const int pair = blockIdx.x * BLOCK + threadIdx.x;
  const float* __restrict__ Wk = kernel_w + k * (C_CH * C_CH);
  const int2 nb = ((const int2*)nbmap)[pair];
  const float4* __restrict__ inrow =
      (const float4*)(in_feature + (long)nb.x * C_CH);
  float a[C_CH];
#pragma unroll
  for (int j = 0; j < 8; ++j) ((float4*)a)[j] = inrow[j];
  float acc[C_CH];
#pragma unroll
  for (int c = 0; c < C_CH; ++c) acc[c] = 0.0f;
#pragma unroll
  for (int i = 0; i < C_CH; ++i) {
    const float av = a[i];
#pragma unroll
    for (int c = 0; c < C_CH; ++c)
      acc[c] = fmaf(av, Wk[i * C_CH + c], acc[c]);
  }
  float* __restrict__ orow = out + (long)nb.y * C_CH;
#pragma unroll
  for (int c = 0; c < C_CH; ++c) atomicAdd(orow + c, acc[c]);
}

// ===========================================================================
extern "C" void kernel_launch(void* const* d_in, const int* in_sizes, int n_in,
                              void* d_out, int out_size, void* d_ws,
                              size_t ws_size, hipStream_t stream) {
  const float* in_feature = (const float*)d_in[0];
  const float* kernel_w   = (const float*)d_in[1];
  const float* bias       = (const float*)d_in[2];
  const int*   nbmap      = (const int*)d_in[3];
  float* out = (float*)d_out;
  const int M = in_sizes[3] / 2;                 // 3,538,944

  // Primary scheme needs: T 27*N_VOX + ovf_cnt N_VOX + ovf S2*N_VOX ints.
  long avail_ints = (long)(ws_size / 4);
  long s2_cap = avail_ints / N_VOX - K3 - 1;
  if (s2_cap >= 16) {
    int S2 = (int)(s2_cap > 32 ? 32 : s2_cap);
    int* T       = (int*)d_ws;                   // [27][N_VOX]
    int* ovf_cnt = T + K3 * N_VOX;               // [N_VOX]
    int* ovf     = ovf_cnt + N_VOX;              // [S2][N_VOX]
    hipMemsetAsync(T, 0xFF, (size_t)K3 * N_VOX * 4, stream);
    hipMemsetAsync(ovf_cnt, 0, (size_t)N_VOX * 4, stream);
    passA_kernel<<<M / BLOCK, BLOCK, 0, stream>>>((const int2*)nbmap, T, M);
    passB_kernel<<<M / BLOCK, BLOCK, 0, stream>>>((const int2*)nbmap, T,
                                                  ovf_cnt, ovf, S2, M);
    gather_dense_kernel<<<N_VOX / BLOCK, BLOCK, 0, stream>>>(
        in_feature, kernel_w, bias, T, ovf_cnt, ovf, out, S2);
    return;
  }

  long s_cap = avail_ints / N_VOX - 1;
  if (s_cap >= 36) {
    int S = (int)(s_cap > 64 ? 64 : s_cap);
    int* cnt   = (int*)d_ws;
    int* slots = cnt + N_VOX;
    hipMemsetAsync(cnt, 0, N_VOX * sizeof(int), stream);
    build_kernel<<<(M + BLOCK - 1) / BLOCK, BLOCK, 0, stream>>>(
        (const int2*)nbmap, cnt, slots, S, M);
    gather_kernel<<<N_VOX / GBLK, GBLK, 0, stream>>>(in_feature, kernel_w,
                                                     bias, cnt, slots, out, S);
    return;
  }

  const int n4 = out_size / 4;
  init_bias_kernel<<<(n4 + BLOCK - 1) / BLOCK, BLOCK, 0, stream>>>(out, bias,
                                                                   n4);
  scatter_conv_kernel<<<M / BLOCK, BLOCK, 0, stream>>>(in_feature, kernel_w,
                                                       nbmap, out);
}

// Round 4
// 510.239 us; speedup vs baseline: 1.8244x; 1.8244x over previous
//
#include <hip/hip_runtime.h>
#include <hip/hip_bf16.h>

// Problem constants (fixed by reference setup_inputs):
//   K3=27, PAIRS_PER_K=131072 (=2^17), N_VOX=262144 (=2^18), C_IN=C_OUT=32
//   M = 3,538,944 pairs. out = [262144][32] fp32.
//
// R1: 113M fp32 atomics = 5.9ms (19G atomic/s at MALL). R2: per-thread LDS
// weight reads = 3x FMA floor. R3: scalar-FMA gather latency-bound at 770us
// (VGPR-starved serialized gathers, 4 waves/SIMD).
// R4: dense ownership table + bf16 MFMA gather (16x16x32, verified layouts),
// cooperative fp32 overflow path, zero atomics on out.

#define N_VOX    262144
#define LOG2_NV  18
#define C_CH     32
#define K3       27
#define LOG2_PPK 17
#define BLOCK    256
#define FLAG_FIN 0x40000000
#define ECAP     4096

typedef __attribute__((ext_vector_type(8))) short bf16x8;
typedef __attribute__((ext_vector_type(4))) float f32x4;

__device__ __forceinline__ unsigned short f2bf(float f) {
  union { __hip_bfloat16 h; unsigned short u; } cv;
  cv.h = __float2bfloat16(f);
  return cv.u;
}

// ---------------------------------------------------------------------------
// Pass A: last-writer-wins claim (plain stores). Self-healing vs any lost
// store: a pair that doesn't see its own p in pass B goes to overflow.
__global__ __launch_bounds__(BLOCK) void passA_kernel(
    const int2* __restrict__ nbmap, int* __restrict__ T, int M) {
  int p = blockIdx.x * BLOCK + threadIdx.x;
  if (p >= M) return;
  int2 nb = nbmap[p];
  int k = p >> LOG2_PPK;
  T[(k << LOG2_NV) + nb.y] = p;
}

// Pass B: winners finalize (FLAG|in_idx); losers -> per-voxel overflow list;
// list overflow (~30 entries expected device-wide) -> emergency list.
__global__ __launch_bounds__(BLOCK) void passB_kernel(
    const int2* __restrict__ nbmap, int* __restrict__ T,
    int* __restrict__ ovf_cnt, int* __restrict__ ovf, int S2,
    int* __restrict__ ecnt, int2* __restrict__ elist, int M) {
  int p = blockIdx.x * BLOCK + threadIdx.x;
  if (p >= M) return;
  int2 nb = nbmap[p];
  int k = p >> LOG2_PPK;
  int idx = (k << LOG2_NV) + nb.y;
  if (T[idx] == p) {
    T[idx] = FLAG_FIN | nb.x;                 // in_idx < 2^18
  } else {
    int pos = atomicAdd(&ovf_cnt[nb.y], 1);
    if (pos < S2) {
      ovf[(pos << LOG2_NV) + nb.y] = (k << LOG2_NV) | nb.x;
    } else {
      int ep = atomicAdd(ecnt, 1);
      if (ep < ECAP) elist[ep] = make_int2(nb.y, (k << LOG2_NV) | nb.x);
    }
  }
}

// ---------------------------------------------------------------------------
// B-fragment prep: Bf[(k*2+t)*64 + lane][j] = bf16(W[k][ (lane>>4)*8+j ]
//                                                  [ t*16 + (lane&15) ])
// i.e. W pre-permuted into the mfma_16x16x32 B-operand lane layout
// (mirror of the verified A layout A[m=lane&15][k=quad*8+j]).
__global__ __launch_bounds__(BLOCK) void bf_prep_kernel(
    const float* __restrict__ kernel_w, unsigned short* __restrict__ Bf) {
  int tid = blockIdx.x * BLOCK + threadIdx.x;
  if (tid >= K3 * 2 * 64) return;
  int lane = tid & 63;
  int kc = tid >> 6;
  int k = kc >> 1, t = kc & 1;
  int i0 = (lane >> 4) * 8;
  int c = t * 16 + (lane & 15);
  union { unsigned short u[8]; uint4 v; } pk;
#pragma unroll
  for (int j = 0; j < 8; ++j)
    pk.u[j] = f2bf(kernel_w[(k << 10) + (i0 + j) * C_CH + c]);
  ((uint4*)Bf)[tid] = pk.v;
}

// ---------------------------------------------------------------------------
// MFMA gather: wave = 16 voxels. Per k: probe T, gather A rows (32B/lane,
// exec-masked), 2x mfma_f32_16x16x32_bf16. Overflow entries processed
// cooperatively in fp32 into LDS aux; one coalesced write-out with bias.
__global__ __launch_bounds__(BLOCK) void gather_mfma_kernel(
    const float* __restrict__ in_feature,
    const float* __restrict__ kernel_w,
    const float* __restrict__ bias,
    const int* __restrict__ T,
    const int* __restrict__ ovf_cnt,
    const int* __restrict__ ovf,
    const unsigned short* __restrict__ Bf,
    float* __restrict__ out, int S2) {
  __shared__ float aux[4][16][33];            // +1 pad: conflict-free merge
  const int wv = threadIdx.x >> 6;
  const int lane = threadIdx.x & 63;
  float* auxw = &aux[wv][0][0];
  for (int i = lane; i < 16 * 33; i += 64) auxw[i] = 0.0f;

  const int vb = (blockIdx.x * 4 + wv) * 16;
  const int r16 = lane & 15;
  const int quad = lane >> 4;
  const int v = vb + r16;

  f32x4 acc0 = {0.f, 0.f, 0.f, 0.f};
  f32x4 acc1 = {0.f, 0.f, 0.f, 0.f};
  const uint4* bfp = (const uint4*)Bf;

#pragma unroll 1
  for (int k = 0; k < K3; ++k) {
    int t = T[(k << LOG2_NV) + v];
    bf16x8 a = (bf16x8)0;
    if (t >= 0) {                              // FLAG|in, else -1
      const float4* ap =
          (const float4*)(in_feature + ((t & 0x3FFFF) << 5) + (quad << 3));
      float4 f0 = ap[0], f1 = ap[1];
      a[0] = (short)f2bf(f0.x); a[1] = (short)f2bf(f0.y);
      a[2] = (short)f2bf(f0.z); a[3] = (short)f2bf(f0.w);
      a[4] = (short)f2bf(f1.x); a[5] = (short)f2bf(f1.y);
      a[6] = (short)f2bf(f1.z); a[7] = (short)f2bf(f1.w);
    }
    uint4 raw0 = bfp[(k * 2 + 0) * 64 + lane];
    uint4 raw1 = bfp[(k * 2 + 1) * 64 + lane];
    bf16x8 b0 = *reinterpret_cast<const bf16x8*>(&raw0);
    bf16x8 b1 = *reinterpret_cast<const bf16x8*>(&raw1);
    acc0 = __builtin_amdgcn_mfma_f32_16x16x32_bf16(a, b0, acc0, 0, 0, 0);
    acc1 = __builtin_amdgcn_mfma_f32_16x16x32_bf16(a, b1, acc1, 0, 0, 0);
  }

  // Overflow: all 64 lanes cooperate per entry (fp32 exact).
  int myc = ovf_cnt[vb + r16];
  if (myc > S2) myc = S2;
  const int c32 = lane & 31, h = lane >> 5;
  for (int r = 0; r < 16; ++r) {
    int n = __shfl(myc, r);
    for (int j = 0; j < n; ++j) {
      int e = ovf[(j << LOG2_NV) + vb + r];    // uniform addr: broadcast
      int k2 = e >> LOG2_NV;
      int in2 = e & 0x3FFFF;
      const float* arow = in_feature + (in2 << 5) + (h << 4);
      const float* wcol = kernel_w + (k2 << 10) + (h << 4) * C_CH + c32;
      float av[16];
#pragma unroll
      for (int i = 0; i < 16; ++i) av[i] = arow[i];
      float psum = 0.f;
#pragma unroll
      for (int i = 0; i < 16; ++i) psum = fmaf(av[i], wcol[i * C_CH], psum);
      psum += __shfl_xor(psum, 32);
      if (h == 0) aux[wv][r][c32] += psum;
    }
  }

  // Epilogue: C/D layout col=lane&15, row=quad*4+reg (verified m89/m91).
  float b0v = bias[r16], b1v = bias[16 + r16];
#pragma unroll
  for (int reg = 0; reg < 4; ++reg) {
    int row = quad * 4 + reg;
    float o0 = acc0[reg] + aux[wv][row][r16] + b0v;
    float o1 = acc1[reg] + aux[wv][row][16 + r16] + b1v;
    out[(vb + row) * C_CH + r16] = o0;
    out[(vb + row) * C_CH + 16 + r16] = o1;
  }
}

// ---------------------------------------------------------------------------
// Emergency finisher: handles the ~tens of entries that overflowed S2.
__global__ __launch_bounds__(BLOCK) void emergency_kernel(
    const float* __restrict__ in_feature, const float* __restrict__ kernel_w,
    const int* __restrict__ ecnt, const int2* __restrict__ elist,
    float* __restrict__ out) {
  int e = blockIdx.x * BLOCK + threadIdx.x;
  int n = *ecnt;
  if (n > ECAP) n = ECAP;
  if (e >= n) return;
  int2 ent = elist[e];
  int v = ent.x, k = ent.y >> LOG2_NV, in = ent.y & 0x3FFFF;
  float a[C_CH];
  const float4* ar = (const float4*)(in_feature + (in << 5));
#pragma unroll
  for (int q = 0; q < 8; ++q) ((float4*)a)[q] = ar[q];
  for (int c = 0; c < C_CH; ++c) {
    float s = 0.f;
#pragma unroll
    for (int i = 0; i < C_CH; ++i)
      s = fmaf(a[i], kernel_w[(k << 10) + i * C_CH + c], s);
    atomicAdd(&out[v * C_CH + c], s);
  }
}

// ---------------------------------------------------------------------------
// Fallback (tiny ws): round-1 direct-atomic version. Correct, slow.
__global__ __launch_bounds__(BLOCK) void init_bias_kernel(
    float* __restrict__ out, const float* __restrict__ bias, int n4) {
  int idx = blockIdx.x * blockDim.x + threadIdx.x;
  if (idx >= n4) return;
  ((float4*)out)[idx] = ((const float4*)bias)[idx & 7];
}

__global__ __launch_bounds__(BLOCK) void scatter_conv_kernel(
    const float* __restrict__ in_feature, const float* __restrict__ kernel_w,
    const int* __restrict__ nbmap, float* __restrict__ out) {
  const int k = blockIdx.x >> 9;
  const int pair = blockIdx.x * BLOCK + threadIdx.x;
  const float* __restrict__ Wk = kernel_w + k * (C_CH * C_CH);
  const int2 nb = ((const int2*)nbmap)[pair];
  const float4* __restrict__ inrow =
      (const float4*)(in_feature + (long)nb.x * C_CH);
  float a[C_CH];
#pragma unroll
  for (int j = 0; j < 8; ++j) ((float4*)a)[j] = inrow[j];
  float acc[C_CH];
#pragma unroll
  for (int c = 0; c < C_CH; ++c) acc[c] = 0.0f;
#pragma unroll
  for (int i = 0; i < C_CH; ++i) {
    const float av = a[i];
#pragma unroll
    for (int c = 0; c < C_CH; ++c)
      acc[c] = fmaf(av, Wk[i * C_CH + c], acc[c]);
  }
  float* __restrict__ orow = out + (long)nb.y * C_CH;
#pragma unroll
  for (int c = 0; c < C_CH; ++c) atomicAdd(orow + c, acc[c]);
}

// ===========================================================================
extern "C" void kernel_launch(void* const* d_in, const int* in_sizes, int n_in,
                              void* d_out, int out_size, void* d_ws,
                              size_t ws_size, hipStream_t stream) {
  const float* in_feature = (const float*)d_in[0];
  const float* kernel_w   = (const float*)d_in[1];
  const float* bias       = (const float*)d_in[2];
  const int*   nbmap      = (const int*)d_in[3];
  float* out = (float*)d_out;
  const int M = in_sizes[3] / 2;                 // 3,538,944

  // ws layout (ints): T1[27*N] | ovf_cnt[N] | ecnt[64] | elist[8192]
  //                   | Bf[13824] | ovf[S2*N]
  const long FIXED = 64 + 2 * ECAP + 13824;
  long ws_ints = (long)(ws_size / 4);
  long s2_cap = (ws_ints - FIXED) / N_VOX - (K3 + 1);
  int S2 = (int)(s2_cap > 15 ? 15 : s2_cap);

  if (S2 < 4) {
    const int n4 = out_size / 4;
    init_bias_kernel<<<(n4 + BLOCK - 1) / BLOCK, BLOCK, 0, stream>>>(out, bias,
                                                                     n4);
    scatter_conv_kernel<<<M / BLOCK, BLOCK, 0, stream>>>(in_feature, kernel_w,
                                                         nbmap, out);
    return;
  }

  int* T        = (int*)d_ws;                       // [27][N_VOX]
  int* ovf_cnt  = T + (long)K3 * N_VOX;             // [N_VOX]
  int* ecnt     = ovf_cnt + N_VOX;                  // [64] (use [0])
  int2* elist   = (int2*)(ecnt + 64);               // [ECAP]
  unsigned short* Bf = (unsigned short*)(ecnt + 64 + 2 * ECAP);  // [27648]
  int* ovf      = (int*)(Bf + 2 * 13824);           // [S2][N_VOX]

  hipMemsetAsync(T, 0xFF, (size_t)K3 * N_VOX * 4, stream);
  hipMemsetAsync(ovf_cnt, 0, (size_t)(N_VOX + 64) * 4, stream);

  bf_prep_kernel<<<(K3 * 2 * 64 + BLOCK - 1) / BLOCK, BLOCK, 0, stream>>>(
      kernel_w, Bf);
  passA_kernel<<<M / BLOCK, BLOCK, 0, stream>>>((const int2*)nbmap, T, M);
  passB_kernel<<<M / BLOCK, BLOCK, 0, stream>>>((const int2*)nbmap, T,
                                                ovf_cnt, ovf, S2, ecnt, elist,
                                                M);
  gather_mfma_kernel<<<N_VOX / 64, BLOCK, 0, stream>>>(
      in_feature, kernel_w, bias, T, ovf_cnt, ovf, Bf, out, S2);
  emergency_kernel<<<ECAP / BLOCK, BLOCK, 0, stream>>>(in_feature, kernel_w,
                                                       ecnt, elist, out);
}